// Round 10
// baseline (52.143 us; speedup 1.0000x reference)
//
#include <hip/hip_runtime.h>
#include <hip/hip_bf16.h>
#include <hip/hip_fp16.h>
#include <cfloat>

// Problem constants
#define BB   16
#define LL   4096
#define CC   9
#define DIN  512
#define DOUT 128
#define VV   96

// LDS geometry
#define BLD  536                 // B row stride in halves (512 + 24): 2-way max conflicts
#define SLD  97                  // S row stride in f32
#define PELD 136                 // PE row stride in halves
#define BBYTES (VV * BLD * 2)    // 102912; S region (256*97*4 = 99328) fits inside

typedef _Float16 f16x8 __attribute__((ext_vector_type(8)));
typedef __attribute__((ext_vector_type(4))) float f32x4;

__device__ __forceinline__ unsigned int pk2(float lo, float hi) {
    return __builtin_bit_cast(unsigned int, __builtin_amdgcn_cvt_pkrtz(lo, hi));
}

// ---------------------------------------------------------------------------
// Kernel 1: PW[v][k] = sum_o PE[v][o]*W[o][k] -> fp16; y==0 blocks also cvt PEh.
// ---------------------------------------------------------------------------
__global__ __launch_bounds__(128)
void pw_kernel(const float* __restrict__ W,    // [DOUT][DIN]
               const float* __restrict__ PE,   // [VV][DOUT]
               __half*      __restrict__ PW,   // [VV][DIN]
               __half*      __restrict__ PEh)  // [VV][DOUT]
{
    const int v = blockIdx.x;                       // 0..95
    const int k = blockIdx.y * 128 + threadIdx.x;   // 0..511
    const float* per = PE + v * DOUT;
    float a = 0.f;
    #pragma unroll 8
    for (int o = 0; o < DOUT; ++o)
        a = fmaf(per[o], W[(size_t)o * DIN + k], a);
    PW[(size_t)v * DIN + k] = __float2half_rn(a);
    if (blockIdx.y == 0)
        PEh[(size_t)v * DOUT + threadIdx.x] = __float2half_rn(per[threadIdx.x]);
}

// ---------------------------------------------------------------------------
// Kernel 2: fused  S = X·PW^T (MFMA f16)  ->  softmax(S[ci])  ->  PV from PEh.
// 1024 threads = 16 waves; each wave 16 rows x 96 cols; grid 256 (1 block/CU).
// ---------------------------------------------------------------------------
__global__ __launch_bounds__(1024)
void attn_kernel(const float*  __restrict__ X,     // [B*L][DIN]
                 const __half* __restrict__ PW,    // [VV][DIN]
                 const __half* __restrict__ PEh,   // [VV][DOUT]
                 const int*    __restrict__ CIDX,  // [B*L][CC]
                 const int*    __restrict__ CMASK, // [B*L][CC]
                 const int*    __restrict__ SLEN,  // [B]
                 float*        __restrict__ OUT)   // [B*L][DOUT]
{
    __shared__ __align__(16) unsigned char lds_raw[BBYTES + VV * PELD * 2]; // 129024 B
    __half* Blds  = (__half*)lds_raw;                 // [VV][BLD] halves
    float*  Slds  = (float*)lds_raw;                  // [256][SLD] f32 (after K-loop)
    __half* PElds = (__half*)(lds_raw + BBYTES);      // [VV][PELD] halves

    const int t    = threadIdx.x;
    const int lane = t & 63;
    const int fr   = lane & 15;        // A row / B col within frag
    const int q8   = (lane >> 4) * 8;  // k sub-offset
    const int wid  = t >> 6;           // 0..15
    const int row0 = blockIdx.x * 256;
    const int wrow = row0 + wid * 16 + fr;   // this lane's A row (global)

    // ---- X prefetch pointers (independent of LDS staging) ----
    const float* xr = X + (size_t)wrow * DIN + q8;

    float4 A0a, A0b, A1a, A1b, A2a, A2b, A3a, A3b;
#define ISSUE(BUF, KK) { BUF##a = *(const float4*)(xr + (KK) * 32); \
                         BUF##b = *(const float4*)(xr + (KK) * 32 + 4); }
    ISSUE(A0, 0) ISSUE(A1, 1) ISSUE(A2, 2) ISSUE(A3, 3)

    // ---- stage B (PW): 6144 uint4 chunks, 6 per thread ----
    #pragma unroll
    for (int it = 0; it < 6; ++it) {
        int chunk = t + it * 1024;
        int v = chunk >> 6, kq = chunk & 63;
        uint4 d = *(const uint4*)(PW + (size_t)v * DIN + kq * 8);
        *(uint4*)&Blds[v * BLD + kq * 8] = d;
    }
    // ---- stage PEh: 1536 chunks ----
    if (t < 1536) {
        int v = t >> 4, kq = t & 15;
        *(uint4*)&PElds[v * PELD + kq * 8] =
            *(const uint4*)(PEh + (size_t)v * DOUT + kq * 8);
    }
    if (t < 512) {
        int c2 = t + 1024;
        int v2 = c2 >> 4, k2 = c2 & 15;
        *(uint4*)&PElds[v2 * PELD + k2 * 8] =
            *(const uint4*)(PEh + (size_t)v2 * DOUT + k2 * 8);
    }
    __syncthreads();

    // ---- K-loop: 16 steps, depth-4 named prefetch ----
    f32x4 acc[6];
    #pragma unroll
    for (int nf = 0; nf < 6; ++nf) acc[nf] = (f32x4)0.f;

#define USE(BUF, KK) {                                                        \
        uint4 up;                                                             \
        up.x = pk2(BUF##a.x, BUF##a.y); up.y = pk2(BUF##a.z, BUF##a.w);       \
        up.z = pk2(BUF##b.x, BUF##b.y); up.w = pk2(BUF##b.z, BUF##b.w);       \
        f16x8 af = __builtin_bit_cast(f16x8, up);                             \
        _Pragma("unroll")                                                     \
        for (int nf = 0; nf < 6; ++nf) {                                      \
            f16x8 bf = *(const f16x8*)&Blds[(nf * 16 + fr) * BLD + (KK) * 32 + q8]; \
            acc[nf] = __builtin_amdgcn_mfma_f32_16x16x32_f16(af, bf, acc[nf], 0, 0, 0); \
        }                                                                     \
    }

    USE(A0, 0)  ISSUE(A0, 4)
    USE(A1, 1)  ISSUE(A1, 5)
    USE(A2, 2)  ISSUE(A2, 6)
    USE(A3, 3)  ISSUE(A3, 7)
    USE(A0, 4)  ISSUE(A0, 8)
    USE(A1, 5)  ISSUE(A1, 9)
    USE(A2, 6)  ISSUE(A2, 10)
    USE(A3, 7)  ISSUE(A3, 11)
    USE(A0, 8)  ISSUE(A0, 12)
    USE(A1, 9)  ISSUE(A1, 13)
    USE(A2, 10) ISSUE(A2, 14)
    USE(A3, 11) ISSUE(A3, 15)
    USE(A0, 12)
    USE(A1, 13)
    USE(A2, 14)
    USE(A3, 15)
#undef USE
#undef ISSUE

    // ---- epilogue row mapping + index loads (hide under barriers) ----
    const int r_e  = t >> 2;            // 0..255 local row
    const int sub  = t & 3;             // 32-dim block
    const int grow = row0 + r_e;
    int ci[CC], vmw[CC];
    #pragma unroll
    for (int c = 0; c < CC; ++c) ci[c]  = CIDX[(size_t)grow * CC + c];
    #pragma unroll
    for (int c = 0; c < CC; ++c) vmw[c] = CMASK[(size_t)grow * CC + c];

    __syncthreads();   // all MFMAs done: B region reusable as S

    // ---- write S tile: D layout col=lane&15, row=(lane>>4)*4+j ----
    #pragma unroll
    for (int nf = 0; nf < 6; ++nf) {
        const int col = nf * 16 + fr;
        const int rb  = wid * 16 + (lane >> 4) * 4;
        #pragma unroll
        for (int j = 0; j < 4; ++j)
            Slds[(rb + j) * SLD + col] = acc[nf][j];
    }
    __syncthreads();

    // ---- softmax over gathered scores ----
    const int  b     = grow >> 12;
    const int  l     = grow & (LL - 1);
    const bool inlen = l < SLEN[b];

    float sc[CC];
    #pragma unroll
    for (int c = 0; c < CC; ++c) sc[c] = Slds[r_e * SLD + ci[c]];

    bool any = false;
    float mx = -FLT_MAX;
    #pragma unroll
    for (int c = 0; c < CC; ++c)
        if (vmw[c]) { mx = fmaxf(mx, sc[c]); any = true; }
    float e[CC];
    float den = 0.f;
    #pragma unroll
    for (int c = 0; c < CC; ++c) {
        e[c] = vmw[c] ? __expf(sc[c] - mx) : 0.f;
        den += e[c];
    }
    const float scale = (any && inlen) ? (1.f / den) : 0.f;

    // ---- PV: out[sub*32 .. +32) = sum_c e[c] * PEh[ci[c]] ----
    float o[32];
    #pragma unroll
    for (int j = 0; j < 32; ++j) o[j] = 0.f;
    #pragma unroll
    for (int c = 0; c < CC; ++c) {
        const float w = e[c];
        const __half* pe = PElds + ci[c] * PELD + sub * 32;
        #pragma unroll
        for (int q = 0; q < 4; ++q) {
            uint4 u = *(const uint4*)(pe + q * 8);
            __half2 h0 = __builtin_bit_cast(__half2, u.x);
            __half2 h1 = __builtin_bit_cast(__half2, u.y);
            __half2 h2 = __builtin_bit_cast(__half2, u.z);
            __half2 h3 = __builtin_bit_cast(__half2, u.w);
            o[q * 8 + 0] = fmaf(w, __half2float(h0.x), o[q * 8 + 0]);
            o[q * 8 + 1] = fmaf(w, __half2float(h0.y), o[q * 8 + 1]);
            o[q * 8 + 2] = fmaf(w, __half2float(h1.x), o[q * 8 + 2]);
            o[q * 8 + 3] = fmaf(w, __half2float(h1.y), o[q * 8 + 3]);
            o[q * 8 + 4] = fmaf(w, __half2float(h2.x), o[q * 8 + 4]);
            o[q * 8 + 5] = fmaf(w, __half2float(h2.y), o[q * 8 + 5]);
            o[q * 8 + 6] = fmaf(w, __half2float(h3.x), o[q * 8 + 6]);
            o[q * 8 + 7] = fmaf(w, __half2float(h3.y), o[q * 8 + 7]);
        }
    }

    float* op = OUT + (size_t)grow * DOUT + sub * 32;
    #pragma unroll
    for (int q = 0; q < 8; ++q) {
        float4 v = make_float4(o[q * 4 + 0] * scale, o[q * 4 + 1] * scale,
                               o[q * 4 + 2] * scale, o[q * 4 + 3] * scale);
        *(float4*)(op + q * 4) = v;
    }
}

extern "C" void kernel_launch(void* const* d_in, const int* in_sizes, int n_in,
                              void* d_out, int out_size, void* d_ws, size_t ws_size,
                              hipStream_t stream) {
    const float* X  = (const float*)d_in[0];
    const float* W  = (const float*)d_in[1];
    const float* PE = (const float*)d_in[2];
    const int*   CI = (const int*)d_in[3];
    const int*   CM = (const int*)d_in[4];
    const int*   SL = (const int*)d_in[5];
    float* OUT = (float*)d_out;
    __half* PW  = (__half*)d_ws;                       // 96*512*2 = 96 KiB
    __half* PEh = (__half*)d_ws + (size_t)VV * DIN;    // +96*128*2 = 24 KiB

    hipLaunchKernelGGL(pw_kernel, dim3(VV, 4), dim3(128), 0, stream, W, PE, PW, PEh);

    const int rows = BB * LL;            // 65536
    hipLaunchKernelGGL(attn_kernel, dim3(rows / 256), dim3(1024), 0, stream,
                       X, PW, PEh, CI, CM, SL, OUT);
}